// Round 1
// baseline (769.151 us; speedup 1.0000x reference)
//
#include <hip/hip_runtime.h>
#include <hip/hip_bf16.h>

#define B_ 8192
#define D_ 3072
#define C_ 512
#define E_ 8

#define BM 128
#define BN 128
#define BK 32
#define LDT 40   // padded LDS leading dim (elements); 80B rows keep 16B align, spread banks

typedef float  floatx4 __attribute__((ext_vector_type(4)));
typedef __bf16 bf16x8  __attribute__((ext_vector_type(8)));
typedef __bf16 bf16x4  __attribute__((ext_vector_type(4)));

__device__ inline bf16x4 cvt4(float4 v) {
    bf16x4 o;
    o[0] = (__bf16)v.x; o[1] = (__bf16)v.y; o[2] = (__bf16)v.z; o[3] = (__bf16)v.w;
    return o;
}

// ---------------- routing ----------------
__global__ void k_count(const int* __restrict__ label, int* __restrict__ counts) {
    int b = blockIdx.x * blockDim.x + threadIdx.x;
    if (b < B_) atomicAdd(&counts[label[b]], 1);
}

__global__ void k_offsets(const int* __restrict__ counts, int* __restrict__ offsets) {
    if (threadIdx.x == 0 && blockIdx.x == 0) {
        int s = 0;
        for (int e = 0; e < E_; ++e) { offsets[e] = s; s += counts[e]; }
    }
}

__global__ void k_scatter(const int* __restrict__ label, const int* __restrict__ offsets,
                          int* __restrict__ cursors, int* __restrict__ row_ids) {
    int b = blockIdx.x * blockDim.x + threadIdx.x;
    if (b < B_) {
        int e = label[b];
        int p = atomicAdd(&cursors[e], 1);
        row_ids[offsets[e] + p] = b;
    }
}

// ---------------- encoder: code = relu(X @ Wenc^T + benc), bf16 out ----------------
__global__ __launch_bounds__(256)
void enc_kernel(const float* __restrict__ img, const float* __restrict__ Wenc,
                const float* __restrict__ benc, const int* __restrict__ row_ids,
                const int* __restrict__ counts, const int* __restrict__ offsets,
                __bf16* __restrict__ code)
{
    const int e   = blockIdx.z;
    const int cnt = counts[e];
    const int m0  = blockIdx.y * BM;
    if (m0 >= cnt) return;
    const int off = offsets[e];
    const int n0  = blockIdx.x * BN;

    __shared__ __bf16 As[BM][LDT];
    __shared__ __bf16 Bs[BN][LDT];

    const int tid  = threadIdx.x;
    const int lane = tid & 63;
    const int wave = tid >> 6;
    const int wm = wave >> 1, wn = wave & 1;

    const float* Wbase = Wenc + (size_t)e * C_ * D_;

    // staging geometry fixed across K-steps: thread handles 4 passes of float4
    const float* aptr[4]; bool avalid[4];
    const float* bptr[4];
    int sr[4], sc[4];
    #pragma unroll
    for (int p = 0; p < 4; ++p) {
        int idx = p * 256 + tid;       // 0..1023
        int r = idx >> 3;              // 0..127
        int c = (idx & 7) << 2;        // 0,4,..,28
        sr[p] = r; sc[p] = c;
        int g = m0 + r;
        avalid[p] = (g < cnt);
        int orig = avalid[p] ? row_ids[off + g] : 0;
        aptr[p] = img + (size_t)orig * D_ + c;
        bptr[p] = Wbase + (size_t)(n0 + r) * D_ + c;
    }

    floatx4 acc[4][4];
    #pragma unroll
    for (int i = 0; i < 4; ++i)
        #pragma unroll
        for (int j = 0; j < 4; ++j)
            acc[i][j] = (floatx4){0.f, 0.f, 0.f, 0.f};

    const int fr = lane & 15;
    const int kq = (lane >> 4) << 3;

    for (int k0 = 0; k0 < D_; k0 += BK) {
        #pragma unroll
        for (int p = 0; p < 4; ++p) {
            float4 v = avalid[p] ? *(const float4*)(aptr[p] + k0)
                                 : make_float4(0.f, 0.f, 0.f, 0.f);
            *(bf16x4*)&As[sr[p]][sc[p]] = cvt4(v);
        }
        #pragma unroll
        for (int p = 0; p < 4; ++p) {
            float4 v = *(const float4*)(bptr[p] + k0);
            *(bf16x4*)&Bs[sr[p]][sc[p]] = cvt4(v);
        }
        __syncthreads();
        bf16x8 af[4], bfb[4];
        #pragma unroll
        for (int i = 0; i < 4; ++i) af[i]  = *(const bf16x8*)&As[wm * 64 + i * 16 + fr][kq];
        #pragma unroll
        for (int i = 0; i < 4; ++i) bfb[i] = *(const bf16x8*)&Bs[wn * 64 + i * 16 + fr][kq];
        #pragma unroll
        for (int mt = 0; mt < 4; ++mt)
            #pragma unroll
            for (int nt = 0; nt < 4; ++nt)
                acc[mt][nt] = __builtin_amdgcn_mfma_f32_16x16x32_bf16(af[mt], bfb[nt], acc[mt][nt], 0, 0, 0);
        __syncthreads();
    }

    const int rq = (lane >> 4) << 2;
    #pragma unroll
    for (int nt = 0; nt < 4; ++nt) {
        int gcol = n0 + wn * 64 + nt * 16 + fr;
        float bias = benc[e * C_ + gcol];
        #pragma unroll
        for (int mt = 0; mt < 4; ++mt) {
            #pragma unroll
            for (int reg = 0; reg < 4; ++reg) {
                int g = m0 + wm * 64 + mt * 16 + rq + reg;
                if (g < cnt) {
                    float v = acc[mt][nt][reg] + bias;
                    v = v > 0.f ? v : 0.f;
                    code[(size_t)(off + g) * C_ + gcol] = (__bf16)v;
                }
            }
        }
    }
}

// ---------------- decoder: dec = code @ Wdec^T + bdec, scatter + fused loss ----------------
__global__ __launch_bounds__(256)
void dec_kernel(const float* __restrict__ img, const float* __restrict__ Wdec,
                const float* __restrict__ bdec, const int* __restrict__ row_ids,
                const int* __restrict__ counts, const int* __restrict__ offsets,
                const __bf16* __restrict__ code, float* __restrict__ decoded,
                double* __restrict__ loss_acc)
{
    const int e   = blockIdx.z;
    const int cnt = counts[e];
    const int m0  = blockIdx.y * BM;
    if (m0 >= cnt) return;
    const int off = offsets[e];
    const int n0  = blockIdx.x * BN;

    __shared__ __bf16 As[BM][LDT];
    __shared__ __bf16 Bs[BN][LDT];
    __shared__ float red[4];

    const int tid  = threadIdx.x;
    const int lane = tid & 63;
    const int wave = tid >> 6;
    const int wm = wave >> 1, wn = wave & 1;

    const float* Wbase = Wdec + (size_t)e * D_ * C_;

    // A staging: bf16 source, 2 passes of 16B per thread
    const __bf16* aptr[2]; bool avalid[2]; int asr[2], asc[2];
    #pragma unroll
    for (int p = 0; p < 2; ++p) {
        int idx = p * 256 + tid;       // 0..511
        int r = idx >> 2;              // 0..127
        int c = (idx & 3) << 3;        // 0,8,16,24
        asr[p] = r; asc[p] = c;
        int g = m0 + r;
        avalid[p] = (g < cnt);
        aptr[p] = code + (size_t)(off + (avalid[p] ? g : 0)) * C_ + c;
    }
    // B staging: fp32 source, 4 passes of float4
    const float* bptr[4]; int bsr[4], bsc[4];
    #pragma unroll
    for (int p = 0; p < 4; ++p) {
        int idx = p * 256 + tid;
        int r = idx >> 3;
        int c = (idx & 7) << 2;
        bsr[p] = r; bsc[p] = c;
        bptr[p] = Wbase + (size_t)(n0 + r) * C_ + c;
    }

    floatx4 acc[4][4];
    #pragma unroll
    for (int i = 0; i < 4; ++i)
        #pragma unroll
        for (int j = 0; j < 4; ++j)
            acc[i][j] = (floatx4){0.f, 0.f, 0.f, 0.f};

    const int fr = lane & 15;
    const int kq = (lane >> 4) << 3;

    const bf16x8 zf = {(__bf16)0.f, (__bf16)0.f, (__bf16)0.f, (__bf16)0.f,
                       (__bf16)0.f, (__bf16)0.f, (__bf16)0.f, (__bf16)0.f};

    for (int k0 = 0; k0 < C_; k0 += BK) {
        #pragma unroll
        for (int p = 0; p < 2; ++p) {
            bf16x8 v = avalid[p] ? *(const bf16x8*)(aptr[p] + k0) : zf;
            *(bf16x8*)&As[asr[p]][asc[p]] = v;
        }
        #pragma unroll
        for (int p = 0; p < 4; ++p) {
            float4 v = *(const float4*)(bptr[p] + k0);
            *(bf16x4*)&Bs[bsr[p]][bsc[p]] = cvt4(v);
        }
        __syncthreads();
        bf16x8 af[4], bfb[4];
        #pragma unroll
        for (int i = 0; i < 4; ++i) af[i]  = *(const bf16x8*)&As[wm * 64 + i * 16 + fr][kq];
        #pragma unroll
        for (int i = 0; i < 4; ++i) bfb[i] = *(const bf16x8*)&Bs[wn * 64 + i * 16 + fr][kq];
        #pragma unroll
        for (int mt = 0; mt < 4; ++mt)
            #pragma unroll
            for (int nt = 0; nt < 4; ++nt)
                acc[mt][nt] = __builtin_amdgcn_mfma_f32_16x16x32_bf16(af[mt], bfb[nt], acc[mt][nt], 0, 0, 0);
        __syncthreads();
    }

    const int rq = (lane >> 4) << 2;
    float lsum = 0.f;
    #pragma unroll
    for (int nt = 0; nt < 4; ++nt) {
        int gcol = n0 + wn * 64 + nt * 16 + fr;
        float bias = bdec[e * D_ + gcol];
        #pragma unroll
        for (int mt = 0; mt < 4; ++mt) {
            #pragma unroll
            for (int reg = 0; reg < 4; ++reg) {
                int g = m0 + wm * 64 + mt * 16 + rq + reg;
                if (g < cnt) {
                    int orig = row_ids[off + g];
                    float v = acc[mt][nt][reg] + bias;
                    decoded[(size_t)orig * D_ + gcol] = v;
                    float d = v - img[(size_t)orig * D_ + gcol];
                    lsum += d * d;
                }
            }
        }
    }
    // block reduce -> one double atomic per block
    #pragma unroll
    for (int o = 32; o > 0; o >>= 1) lsum += __shfl_down(lsum, o, 64);
    if (lane == 0) red[wave] = lsum;
    __syncthreads();
    if (tid == 0) atomicAdd(loss_acc, (double)(red[0] + red[1] + red[2] + red[3]));
}

__global__ void k_final(const double* __restrict__ loss_acc, float* __restrict__ out) {
    if (threadIdx.x == 0 && blockIdx.x == 0)
        out[0] = (float)(*loss_acc / (double)((size_t)B_ * (size_t)D_));
}

// ---------------- launch ----------------
extern "C" void kernel_launch(void* const* d_in, const int* in_sizes, int n_in,
                              void* d_out, int out_size, void* d_ws, size_t ws_size,
                              hipStream_t stream)
{
    const float* img   = (const float*)d_in[0];
    const int*   label = (const int*)d_in[1];
    const float* Wenc  = (const float*)d_in[2];
    const float* benc  = (const float*)d_in[3];
    const float* Wdec  = (const float*)d_in[4];
    const float* bdec  = (const float*)d_in[5];
    float* out = (float*)d_out;

    char* ws = (char*)d_ws;
    int*    counts  = (int*)(ws + 0);     // 8 ints, zeroed
    int*    cursors = (int*)(ws + 32);    // 8 ints, zeroed
    int*    offsets = (int*)(ws + 64);    // 8 ints
    double* loss    = (double*)(ws + 96); // zeroed
    int*    row_ids = (int*)(ws + 128);   // 8192 ints
    __bf16* code    = (__bf16*)(ws + 65536); // B*C bf16 = 8 MB, gathered order

    hipMemsetAsync(d_ws, 0, 128, stream);
    k_count  <<<dim3(B_ / 256), dim3(256), 0, stream>>>(label, counts);
    k_offsets<<<dim3(1),        dim3(64),  0, stream>>>(counts, offsets);
    k_scatter<<<dim3(B_ / 256), dim3(256), 0, stream>>>(label, offsets, cursors, row_ids);
    enc_kernel<<<dim3(C_ / BN, B_ / BM, E_), dim3(256), 0, stream>>>(
        img, Wenc, benc, row_ids, counts, offsets, code);
    dec_kernel<<<dim3(D_ / BN, B_ / BM, E_), dim3(256), 0, stream>>>(
        img, Wdec, bdec, row_ids, counts, offsets, code, out + 1, loss);
    k_final<<<dim3(1), dim3(64), 0, stream>>>(loss, out);
}

// Round 2
// 620.724 us; speedup vs baseline: 1.2391x; 1.2391x over previous
//
#include <hip/hip_runtime.h>
#include <hip/hip_bf16.h>

#define B_ 8192
#define D_ 3072
#define C_ 512
#define E_ 8

#define BK 32
#define LDT 40   // padded LDS leading dim (elements)

typedef float  floatx4 __attribute__((ext_vector_type(4)));
typedef __bf16 bf16x8  __attribute__((ext_vector_type(8)));
typedef __bf16 bf16x4  __attribute__((ext_vector_type(4)));

__device__ inline bf16x4 cvt4(float4 v) {
    bf16x4 o;
    o[0] = (__bf16)v.x; o[1] = (__bf16)v.y; o[2] = (__bf16)v.z; o[3] = (__bf16)v.w;
    return o;
}

// ---------------- routing ----------------
__global__ void k_count(const int* __restrict__ label, int* __restrict__ counts) {
    int b = blockIdx.x * blockDim.x + threadIdx.x;
    if (b < B_) atomicAdd(&counts[label[b]], 1);
}

__global__ void k_offsets(const int* __restrict__ counts, int* __restrict__ offsets) {
    if (threadIdx.x == 0 && blockIdx.x == 0) {
        int s = 0;
        for (int e = 0; e < E_; ++e) { offsets[e] = s; s += counts[e]; }
    }
}

__global__ void k_scatter(const int* __restrict__ label, const int* __restrict__ offsets,
                          int* __restrict__ cursors, int* __restrict__ row_ids) {
    int b = blockIdx.x * blockDim.x + threadIdx.x;
    if (b < B_) {
        int e = label[b];
        int p = atomicAdd(&cursors[e], 1);
        row_ids[offsets[e] + p] = b;
    }
}

// ---------------- encoder: code = relu(X @ Wenc^T + benc), bf16 out ----------------
// BM=64, BN=128: ~550 working blocks (2/CU). 4 waves as 2x2, wave-tile 32x64.
// Pipelined: register prefetch 2 K-steps ahead, LDS double-buffer, 1 barrier/step.
#define EBM 64
#define EBN 128
__global__ __launch_bounds__(256, 3)
void enc_kernel(const float* __restrict__ img, const float* __restrict__ Wenc,
                const float* __restrict__ benc, const int* __restrict__ row_ids,
                const int* __restrict__ counts, const int* __restrict__ offsets,
                __bf16* __restrict__ code)
{
    const int e   = blockIdx.z;
    const int cnt = counts[e];
    const int m0  = blockIdx.y * EBM;
    if (m0 >= cnt) return;
    const int off = offsets[e];
    const int n0  = blockIdx.x * EBN;

    __shared__ __bf16 As[2][EBM][LDT];
    __shared__ __bf16 Bs[2][EBN][LDT];

    const int tid  = threadIdx.x;
    const int lane = tid & 63;
    const int wave = tid >> 6;
    const int wm = wave >> 1, wn = wave & 1;

    const float* Wbase = Wenc + (size_t)e * C_ * D_;

    // A staging: 64x32 fp32 -> 2 float4/thread. B: 128x32 -> 4 float4/thread.
    const float* aptr[2]; bool avalid[2]; int asr[2], asc[2];
    #pragma unroll
    for (int p = 0; p < 2; ++p) {
        int idx = p * 256 + tid;        // 0..511
        int r = idx >> 3;               // 0..63
        int c = (idx & 7) << 2;
        asr[p] = r; asc[p] = c;
        int g = m0 + r;
        avalid[p] = (g < cnt);
        int orig = avalid[p] ? row_ids[off + g] : 0;
        aptr[p] = img + (size_t)orig * D_ + c;
    }
    const float* bptr[4]; int bsr[4], bsc[4];
    #pragma unroll
    for (int p = 0; p < 4; ++p) {
        int idx = p * 256 + tid;        // 0..1023
        int r = idx >> 3;               // 0..127
        int c = (idx & 7) << 2;
        bsr[p] = r; bsc[p] = c;
        bptr[p] = Wbase + (size_t)(n0 + r) * D_ + c;
    }

    floatx4 acc[2][4];
    #pragma unroll
    for (int i = 0; i < 2; ++i)
        #pragma unroll
        for (int j = 0; j < 4; ++j)
            acc[i][j] = (floatx4){0.f, 0.f, 0.f, 0.f};

    const int fr = lane & 15;
    const int kq = (lane >> 4) << 3;

    float4 aR[2], bR[4];
    const float4 z4 = make_float4(0.f, 0.f, 0.f, 0.f);

    // prologue
    #pragma unroll
    for (int p = 0; p < 2; ++p) aR[p] = avalid[p] ? *(const float4*)(aptr[p] + 0) : z4;
    #pragma unroll
    for (int p = 0; p < 4; ++p) bR[p] = *(const float4*)(bptr[p] + 0);
    #pragma unroll
    for (int p = 0; p < 2; ++p) *(bf16x4*)&As[0][asr[p]][asc[p]] = cvt4(aR[p]);
    #pragma unroll
    for (int p = 0; p < 4; ++p) *(bf16x4*)&Bs[0][bsr[p]][bsc[p]] = cvt4(bR[p]);
    #pragma unroll
    for (int p = 0; p < 2; ++p) aR[p] = avalid[p] ? *(const float4*)(aptr[p] + BK) : z4;
    #pragma unroll
    for (int p = 0; p < 4; ++p) bR[p] = *(const float4*)(bptr[p] + BK);
    __syncthreads();

    const int nsteps = D_ / BK;   // 96
    for (int s = 0; s < nsteps; ++s) {
        const int buf = s & 1;
        bf16x8 af[2], bfb[4];
        #pragma unroll
        for (int i = 0; i < 2; ++i) af[i]  = *(const bf16x8*)&As[buf][wm * 32 + i * 16 + fr][kq];
        #pragma unroll
        for (int j = 0; j < 4; ++j) bfb[j] = *(const bf16x8*)&Bs[buf][wn * 64 + j * 16 + fr][kq];
        if (s + 1 < nsteps) {
            #pragma unroll
            for (int p = 0; p < 2; ++p) *(bf16x4*)&As[buf ^ 1][asr[p]][asc[p]] = cvt4(aR[p]);
            #pragma unroll
            for (int p = 0; p < 4; ++p) *(bf16x4*)&Bs[buf ^ 1][bsr[p]][bsc[p]] = cvt4(bR[p]);
            if (s + 2 < nsteps) {
                const int k2 = (s + 2) * BK;
                #pragma unroll
                for (int p = 0; p < 2; ++p) aR[p] = avalid[p] ? *(const float4*)(aptr[p] + k2) : z4;
                #pragma unroll
                for (int p = 0; p < 4; ++p) bR[p] = *(const float4*)(bptr[p] + k2);
            }
        }
        #pragma unroll
        for (int mt = 0; mt < 2; ++mt)
            #pragma unroll
            for (int nt = 0; nt < 4; ++nt)
                acc[mt][nt] = __builtin_amdgcn_mfma_f32_16x16x32_bf16(af[mt], bfb[nt], acc[mt][nt], 0, 0, 0);
        __syncthreads();
    }

    const int rq = (lane >> 4) << 2;
    #pragma unroll
    for (int nt = 0; nt < 4; ++nt) {
        int gcol = n0 + wn * 64 + nt * 16 + fr;
        float bias = benc[e * C_ + gcol];
        #pragma unroll
        for (int mt = 0; mt < 2; ++mt) {
            #pragma unroll
            for (int reg = 0; reg < 4; ++reg) {
                int g = m0 + wm * 32 + mt * 16 + rq + reg;
                if (g < cnt) {
                    float v = acc[mt][nt][reg] + bias;
                    v = v > 0.f ? v : 0.f;
                    code[(size_t)(off + g) * C_ + gcol] = (__bf16)v;
                }
            }
        }
    }
}

// ---------------- decoder: dec = code @ Wdec^T + bdec, scatter + fused loss ----------------
// BM=128, BN=128: ~1700 working blocks (~6/CU). Same pipeline.
#define DBM 128
#define DBN 128
__global__ __launch_bounds__(256, 2)
void dec_kernel(const float* __restrict__ img, const float* __restrict__ Wdec,
                const float* __restrict__ bdec, const int* __restrict__ row_ids,
                const int* __restrict__ counts, const int* __restrict__ offsets,
                const __bf16* __restrict__ code, float* __restrict__ decoded,
                double* __restrict__ loss_acc)
{
    const int e   = blockIdx.z;
    const int cnt = counts[e];
    const int m0  = blockIdx.y * DBM;
    if (m0 >= cnt) return;
    const int off = offsets[e];
    const int n0  = blockIdx.x * DBN;

    __shared__ __bf16 As[2][DBM][LDT];
    __shared__ __bf16 Bs[2][DBN][LDT];
    __shared__ float red[4];

    const int tid  = threadIdx.x;
    const int lane = tid & 63;
    const int wave = tid >> 6;
    const int wm = wave >> 1, wn = wave & 1;

    const float* Wbase = Wdec + (size_t)e * D_ * C_;

    // A staging: 128x32 bf16 -> 2x bf16x8/thread. B: 128x32 fp32 -> 4 float4/thread.
    const __bf16* aptr[2]; bool avalid[2]; int asr[2], asc[2];
    #pragma unroll
    for (int p = 0; p < 2; ++p) {
        int idx = p * 256 + tid;        // 0..511
        int r = idx >> 2;               // 0..127
        int c = (idx & 3) << 3;         // 0,8,16,24
        asr[p] = r; asc[p] = c;
        int g = m0 + r;
        avalid[p] = (g < cnt);
        aptr[p] = code + (size_t)(off + (avalid[p] ? g : 0)) * C_ + c;
    }
    const float* bptr[4]; int bsr[4], bsc[4];
    #pragma unroll
    for (int p = 0; p < 4; ++p) {
        int idx = p * 256 + tid;
        int r = idx >> 3;
        int c = (idx & 7) << 2;
        bsr[p] = r; bsc[p] = c;
        bptr[p] = Wbase + (size_t)(n0 + r) * C_ + c;
    }

    floatx4 acc[4][4];
    #pragma unroll
    for (int i = 0; i < 4; ++i)
        #pragma unroll
        for (int j = 0; j < 4; ++j)
            acc[i][j] = (floatx4){0.f, 0.f, 0.f, 0.f};

    const int fr = lane & 15;
    const int kq = (lane >> 4) << 3;

    const bf16x8 zf = {(__bf16)0.f, (__bf16)0.f, (__bf16)0.f, (__bf16)0.f,
                       (__bf16)0.f, (__bf16)0.f, (__bf16)0.f, (__bf16)0.f};
    bf16x8 aR[2]; float4 bR[4];

    // prologue
    #pragma unroll
    for (int p = 0; p < 2; ++p) aR[p] = avalid[p] ? *(const bf16x8*)(aptr[p] + 0) : zf;
    #pragma unroll
    for (int p = 0; p < 4; ++p) bR[p] = *(const float4*)(bptr[p] + 0);
    #pragma unroll
    for (int p = 0; p < 2; ++p) *(bf16x8*)&As[0][asr[p]][asc[p]] = aR[p];
    #pragma unroll
    for (int p = 0; p < 4; ++p) *(bf16x4*)&Bs[0][bsr[p]][bsc[p]] = cvt4(bR[p]);
    #pragma unroll
    for (int p = 0; p < 2; ++p) aR[p] = avalid[p] ? *(const bf16x8*)(aptr[p] + BK) : zf;
    #pragma unroll
    for (int p = 0; p < 4; ++p) bR[p] = *(const float4*)(bptr[p] + BK);
    __syncthreads();

    const int nsteps = C_ / BK;   // 16
    for (int s = 0; s < nsteps; ++s) {
        const int buf = s & 1;
        bf16x8 af[4], bfb[4];
        #pragma unroll
        for (int i = 0; i < 4; ++i) af[i]  = *(const bf16x8*)&As[buf][wm * 64 + i * 16 + fr][kq];
        #pragma unroll
        for (int j = 0; j < 4; ++j) bfb[j] = *(const bf16x8*)&Bs[buf][wn * 64 + j * 16 + fr][kq];
        if (s + 1 < nsteps) {
            #pragma unroll
            for (int p = 0; p < 2; ++p) *(bf16x8*)&As[buf ^ 1][asr[p]][asc[p]] = aR[p];
            #pragma unroll
            for (int p = 0; p < 4; ++p) *(bf16x4*)&Bs[buf ^ 1][bsr[p]][bsc[p]] = cvt4(bR[p]);
            if (s + 2 < nsteps) {
                const int k2 = (s + 2) * BK;
                #pragma unroll
                for (int p = 0; p < 2; ++p) aR[p] = avalid[p] ? *(const bf16x8*)(aptr[p] + k2) : zf;
                #pragma unroll
                for (int p = 0; p < 4; ++p) bR[p] = *(const float4*)(bptr[p] + k2);
            }
        }
        #pragma unroll
        for (int mt = 0; mt < 4; ++mt)
            #pragma unroll
            for (int nt = 0; nt < 4; ++nt)
                acc[mt][nt] = __builtin_amdgcn_mfma_f32_16x16x32_bf16(af[mt], bfb[nt], acc[mt][nt], 0, 0, 0);
        __syncthreads();
    }

    const int rq = (lane >> 4) << 2;
    float lsum = 0.f;
    #pragma unroll
    for (int nt = 0; nt < 4; ++nt) {
        int gcol = n0 + wn * 64 + nt * 16 + fr;
        float bias = bdec[e * D_ + gcol];
        #pragma unroll
        for (int mt = 0; mt < 4; ++mt) {
            #pragma unroll
            for (int reg = 0; reg < 4; ++reg) {
                int g = m0 + wm * 64 + mt * 16 + rq + reg;
                if (g < cnt) {
                    int orig = row_ids[off + g];
                    float v = acc[mt][nt][reg] + bias;
                    decoded[(size_t)orig * D_ + gcol] = v;
                    float d = v - img[(size_t)orig * D_ + gcol];
                    lsum += d * d;
                }
            }
        }
    }
    #pragma unroll
    for (int o = 32; o > 0; o >>= 1) lsum += __shfl_down(lsum, o, 64);
    if (lane == 0) red[wave] = lsum;
    __syncthreads();
    if (tid == 0) atomicAdd(loss_acc, (double)(red[0] + red[1] + red[2] + red[3]));
}

__global__ void k_final(const double* __restrict__ loss_acc, float* __restrict__ out) {
    if (threadIdx.x == 0 && blockIdx.x == 0)
        out[0] = (float)(*loss_acc / (double)((size_t)B_ * (size_t)D_));
}

// ---------------- launch ----------------
extern "C" void kernel_launch(void* const* d_in, const int* in_sizes, int n_in,
                              void* d_out, int out_size, void* d_ws, size_t ws_size,
                              hipStream_t stream)
{
    const float* img   = (const float*)d_in[0];
    const int*   label = (const int*)d_in[1];
    const float* Wenc  = (const float*)d_in[2];
    const float* benc  = (const float*)d_in[3];
    const float* Wdec  = (const float*)d_in[4];
    const float* bdec  = (const float*)d_in[5];
    float* out = (float*)d_out;

    char* ws = (char*)d_ws;
    int*    counts  = (int*)(ws + 0);     // 8 ints, zeroed
    int*    cursors = (int*)(ws + 32);    // 8 ints, zeroed
    int*    offsets = (int*)(ws + 64);    // 8 ints
    double* loss    = (double*)(ws + 96); // zeroed
    int*    row_ids = (int*)(ws + 128);   // 8192 ints
    __bf16* code    = (__bf16*)(ws + 65536); // B*C bf16 = 8 MB, gathered order

    hipMemsetAsync(d_ws, 0, 128, stream);
    k_count  <<<dim3(B_ / 256), dim3(256), 0, stream>>>(label, counts);
    k_offsets<<<dim3(1),        dim3(64),  0, stream>>>(counts, offsets);
    k_scatter<<<dim3(B_ / 256), dim3(256), 0, stream>>>(label, offsets, cursors, row_ids);
    enc_kernel<<<dim3(C_ / EBN, B_ / EBM, E_), dim3(256), 0, stream>>>(
        img, Wenc, benc, row_ids, counts, offsets, code);
    dec_kernel<<<dim3(D_ / DBN, B_ / DBM, E_), dim3(256), 0, stream>>>(
        img, Wdec, bdec, row_ids, counts, offsets, code, out + 1, loss);
    k_final<<<dim3(1), dim3(64), 0, stream>>>(loss, out);
}

// Round 3
// 564.443 us; speedup vs baseline: 1.3627x; 1.0997x over previous
//
#include <hip/hip_runtime.h>
#include <hip/hip_bf16.h>

#define B_ 8192
#define D_ 3072
#define C_ 512
#define E_ 8

typedef float  floatx4 __attribute__((ext_vector_type(4)));
typedef __bf16 bf16x8  __attribute__((ext_vector_type(8)));
typedef __bf16 bf16x4  __attribute__((ext_vector_type(4)));

__device__ __forceinline__ bf16x4 cvt4(float4 v) {
    bf16x4 o;
    o[0] = (__bf16)v.x; o[1] = (__bf16)v.y; o[2] = (__bf16)v.z; o[3] = (__bf16)v.w;
    return o;
}

// async global->LDS, 16B per lane. LDS dest must be wave-uniform base + lane*16.
__device__ __forceinline__ void dma16(const void* g, void* l) {
    __builtin_amdgcn_global_load_lds(
        (const __attribute__((address_space(1))) unsigned int*)(uintptr_t)g,
        (__attribute__((address_space(3))) unsigned int*)(uintptr_t)l,
        16, 0, 0);
}

// ---------------- routing ----------------
__global__ void k_count(const int* __restrict__ label, int* __restrict__ counts) {
    int b = blockIdx.x * blockDim.x + threadIdx.x;
    if (b < B_) atomicAdd(&counts[label[b]], 1);
}

__global__ void k_offsets(const int* __restrict__ counts, int* __restrict__ offsets) {
    if (threadIdx.x == 0 && blockIdx.x == 0) {
        int s = 0;
        for (int e = 0; e < E_; ++e) { offsets[e] = s; s += counts[e]; }
    }
}

__global__ void k_scatter(const int* __restrict__ label, const int* __restrict__ offsets,
                          int* __restrict__ cursors, int* __restrict__ row_ids) {
    int b = blockIdx.x * blockDim.x + threadIdx.x;
    if (b < B_) {
        int e = label[b];
        int p = atomicAdd(&cursors[e], 1);
        row_ids[offsets[e] + p] = b;
    }
}

// ---------------- prepass: fp32 -> bf16 (img gathered to sorted order, weights) ----
#define D4_ (D_ / 4)
#define NI_ (B_ * D4_)          // img float4 count
#define NW_ (E_ * C_ * D4_)     // per-weight float4 count
__global__ __launch_bounds__(256)
void k_prep(const float4* __restrict__ img4, const int* __restrict__ row_ids,
            const float4* __restrict__ We4, const float4* __restrict__ Wd4,
            bf16x4* __restrict__ imgG4, bf16x4* __restrict__ We16_4,
            bf16x4* __restrict__ Wd16_4)
{
    int i = blockIdx.x * 256 + threadIdx.x;
    const int stride = gridDim.x * 256;
    const int total = NI_ + 2 * NW_;
    for (; i < total; i += stride) {
        if (i < NI_) {
            int row = i / D4_;
            int c   = i - row * D4_;
            float4 v = img4[(size_t)row_ids[row] * D4_ + c];
            imgG4[i] = cvt4(v);
        } else if (i < NI_ + NW_) {
            int j = i - NI_;
            We16_4[j] = cvt4(We4[j]);
        } else {
            int j = i - NI_ - NW_;
            Wd16_4[j] = cvt4(Wd4[j]);
        }
    }
}

// ---------------- encoder: code = relu(imgG @ We16^T + benc), bf16 out ----------------
// 128x128 tile, 512 threads (8 waves as 2x4), wave-tile 64x32.
// global_load_lds staging, LDS dbuf, one barrier per K-step.
__global__ __launch_bounds__(512, 1)
void enc_kernel(const __bf16* __restrict__ imgG, const __bf16* __restrict__ We16,
                const float* __restrict__ benc, const int* __restrict__ counts,
                const int* __restrict__ offsets, __bf16* __restrict__ code)
{
    const int e   = blockIdx.z;
    const int cnt = counts[e];
    const int m0  = blockIdx.y * 128;
    if (m0 >= cnt) return;
    const int off = offsets[e];
    const int n0  = blockIdx.x * 128;

    __shared__ __bf16 As[2][128][32];   // 8 KB per buf
    __shared__ __bf16 Bs[2][128][32];

    const int tid  = threadIdx.x;
    const int lane = tid & 63;
    const int wave = tid >> 6;   // 0..7
    const int wm   = wave >> 2;  // 0..1  (M half)
    const int wn   = wave & 3;   // 0..3  (N quarter)

    // DMA geometry: 512 thr x 16B = 8 KB = one full 128x32 bf16 tile per round
    const int srow = tid >> 2;          // 0..127
    const int scol = (tid & 3) << 3;    // 0,8,16,24 (elements)
    const __bf16* ag = imgG + (size_t)(off + m0 + srow) * D_ + scol;
    const __bf16* bg = We16 + ((size_t)e * C_ + n0 + srow) * D_ + scol;
    char* lA = (char*)&As[0][0][0] + tid * 16;
    char* lB = (char*)&Bs[0][0][0] + tid * 16;

    dma16(ag, lA);
    dma16(bg, lB);

    floatx4 acc[4][2];
    #pragma unroll
    for (int i = 0; i < 4; ++i)
        #pragma unroll
        for (int j = 0; j < 2; ++j)
            acc[i][j] = (floatx4){0.f, 0.f, 0.f, 0.f};

    const int fr = lane & 15;
    const int kq = (lane >> 4) << 3;

    __syncthreads();   // drains prologue DMA

    const int nsteps = D_ / 32;   // 96
    for (int s = 0; s < nsteps; ++s) {
        const int buf = s & 1;
        if (s + 1 < nsteps) {
            const int nb = (buf ^ 1) * 8192;
            dma16(ag + (size_t)(s + 1) * 32, lA + nb);
            dma16(bg + (size_t)(s + 1) * 32, lB + nb);
        }
        bf16x8 af[4], bfb[2];
        #pragma unroll
        for (int i = 0; i < 4; ++i) af[i]  = *(const bf16x8*)&As[buf][wm * 64 + i * 16 + fr][kq];
        #pragma unroll
        for (int j = 0; j < 2; ++j) bfb[j] = *(const bf16x8*)&Bs[buf][wn * 32 + j * 16 + fr][kq];
        #pragma unroll
        for (int mt = 0; mt < 4; ++mt)
            #pragma unroll
            for (int nt = 0; nt < 2; ++nt)
                acc[mt][nt] = __builtin_amdgcn_mfma_f32_16x16x32_bf16(af[mt], bfb[nt], acc[mt][nt], 0, 0, 0);
        __syncthreads();   // waits vmcnt(0): next buf's DMA complete; reads of buf done
    }

    const int rq = (lane >> 4) << 2;
    #pragma unroll
    for (int nt = 0; nt < 2; ++nt) {
        int gcol = n0 + wn * 32 + nt * 16 + fr;
        float bias = benc[e * C_ + gcol];
        #pragma unroll
        for (int mt = 0; mt < 4; ++mt) {
            #pragma unroll
            for (int reg = 0; reg < 4; ++reg) {
                int g = m0 + wm * 64 + mt * 16 + rq + reg;
                if (g < cnt) {
                    float v = acc[mt][nt][reg] + bias;
                    v = v > 0.f ? v : 0.f;
                    code[(size_t)(off + g) * C_ + gcol] = (__bf16)v;
                }
            }
        }
    }
}

// ---------------- decoder: dec = code @ Wd16^T + bdec, scatter + fused loss ------------
// 128x128 tile, 256 threads (2x2 waves), wave-tile 64x64 (m97-exact).
__global__ __launch_bounds__(256, 4)
void dec_kernel(const __bf16* __restrict__ imgG, const __bf16* __restrict__ Wd16,
                const float* __restrict__ bdec, const int* __restrict__ row_ids,
                const int* __restrict__ counts, const int* __restrict__ offsets,
                const __bf16* __restrict__ code, float* __restrict__ decoded,
                double* __restrict__ loss_acc)
{
    const int e   = blockIdx.z;
    const int cnt = counts[e];
    const int m0  = blockIdx.y * 128;
    if (m0 >= cnt) return;
    const int off = offsets[e];
    const int n0  = blockIdx.x * 128;

    __shared__ __bf16 As[2][128][32];
    __shared__ __bf16 Bs[2][128][32];
    __shared__ float red[4];

    const int tid  = threadIdx.x;
    const int lane = tid & 63;
    const int wave = tid >> 6;   // 0..3
    const int wm   = wave >> 1;
    const int wn   = wave & 1;

    // DMA geometry: 256 thr -> 2 rounds per tile (4 KB per round)
    const int r0   = tid >> 2;            // 0..63
    const int scol = (tid & 3) << 3;
    const __bf16* ag0 = code + (size_t)(off + m0 + r0) * C_ + scol;
    const __bf16* ag1 = code + (size_t)(off + m0 + 64 + r0) * C_ + scol;
    const __bf16* bg0 = Wd16 + ((size_t)e * D_ + n0 + r0) * C_ + scol;
    const __bf16* bg1 = Wd16 + ((size_t)e * D_ + n0 + 64 + r0) * C_ + scol;
    char* lA = (char*)&As[0][0][0] + tid * 16;   // round1 dest: +4096
    char* lB = (char*)&Bs[0][0][0] + tid * 16;

    dma16(ag0, lA);  dma16(ag1, lA + 4096);
    dma16(bg0, lB);  dma16(bg1, lB + 4096);

    floatx4 acc[4][4];
    #pragma unroll
    for (int i = 0; i < 4; ++i)
        #pragma unroll
        for (int j = 0; j < 4; ++j)
            acc[i][j] = (floatx4){0.f, 0.f, 0.f, 0.f};

    const int fr = lane & 15;
    const int kq = (lane >> 4) << 3;

    __syncthreads();

    const int nsteps = C_ / 32;   // 16
    for (int s = 0; s < nsteps; ++s) {
        const int buf = s & 1;
        if (s + 1 < nsteps) {
            const int nb = (buf ^ 1) * 8192;
            const size_t ko = (size_t)(s + 1) * 32;
            dma16(ag0 + ko, lA + nb);  dma16(ag1 + ko, lA + nb + 4096);
            dma16(bg0 + ko, lB + nb);  dma16(bg1 + ko, lB + nb + 4096);
        }
        bf16x8 af[4], bfb[4];
        #pragma unroll
        for (int i = 0; i < 4; ++i) af[i]  = *(const bf16x8*)&As[buf][wm * 64 + i * 16 + fr][kq];
        #pragma unroll
        for (int j = 0; j < 4; ++j) bfb[j] = *(const bf16x8*)&Bs[buf][wn * 64 + j * 16 + fr][kq];
        #pragma unroll
        for (int mt = 0; mt < 4; ++mt)
            #pragma unroll
            for (int nt = 0; nt < 4; ++nt)
                acc[mt][nt] = __builtin_amdgcn_mfma_f32_16x16x32_bf16(af[mt], bfb[nt], acc[mt][nt], 0, 0, 0);
        __syncthreads();
    }

    const int rq = (lane >> 4) << 2;
    // hoist row ids / validity (16 per lane)
    int orig[4][4];
    #pragma unroll
    for (int mt = 0; mt < 4; ++mt)
        #pragma unroll
        for (int reg = 0; reg < 4; ++reg) {
            int g = m0 + wm * 64 + mt * 16 + rq + reg;
            orig[mt][reg] = (g < cnt) ? row_ids[off + g] : -1;
        }

    float lsum = 0.f;
    #pragma unroll
    for (int nt = 0; nt < 4; ++nt) {
        int gcol = n0 + wn * 64 + nt * 16 + fr;
        float bias = bdec[e * D_ + gcol];
        #pragma unroll
        for (int mt = 0; mt < 4; ++mt) {
            #pragma unroll
            for (int reg = 0; reg < 4; ++reg) {
                if (orig[mt][reg] >= 0) {
                    int g = m0 + wm * 64 + mt * 16 + rq + reg;
                    float v = acc[mt][nt][reg] + bias;
                    decoded[(size_t)orig[mt][reg] * D_ + gcol] = v;
                    float d = v - (float)imgG[(size_t)(off + g) * D_ + gcol];
                    lsum += d * d;
                }
            }
        }
    }
    #pragma unroll
    for (int o = 32; o > 0; o >>= 1) lsum += __shfl_down(lsum, o, 64);
    if (lane == 0) red[wave] = lsum;
    __syncthreads();
    if (tid == 0) atomicAdd(loss_acc, (double)(red[0] + red[1] + red[2] + red[3]));
}

__global__ void k_final(const double* __restrict__ loss_acc, float* __restrict__ out) {
    if (threadIdx.x == 0 && blockIdx.x == 0)
        out[0] = (float)(*loss_acc / (double)((size_t)B_ * (size_t)D_));
}

// ---------------- launch ----------------
extern "C" void kernel_launch(void* const* d_in, const int* in_sizes, int n_in,
                              void* d_out, int out_size, void* d_ws, size_t ws_size,
                              hipStream_t stream)
{
    const float* img   = (const float*)d_in[0];
    const int*   label = (const int*)d_in[1];
    const float* Wenc  = (const float*)d_in[2];
    const float* benc  = (const float*)d_in[3];
    const float* Wdec  = (const float*)d_in[4];
    const float* bdec  = (const float*)d_in[5];
    float* out = (float*)d_out;

    char* ws = (char*)d_ws;
    int*    counts  = (int*)(ws + 0);
    int*    cursors = (int*)(ws + 32);
    int*    offsets = (int*)(ws + 64);
    double* loss    = (double*)(ws + 96);
    int*    row_ids = (int*)(ws + 128);
    // bf16 scratch (sizes include 128 rows of tail slack for OOB tile reads):
    __bf16* code = (__bf16*)(ws + 65536);                               // (B+128)*C*2 = 8,519,680
    __bf16* imgG = (__bf16*)(ws + 65536 + 8519680);                     // (B+128)*D*2 = 51,118,080
    __bf16* We16 = (__bf16*)(ws + 65536 + 8519680 + 51118080);          // E*C*D*2 = 25,165,824
    __bf16* Wd16 = (__bf16*)(ws + 65536 + 8519680 + 51118080 + 25165824);
    // total ws use ~105 MB

    hipMemsetAsync(d_ws, 0, 128, stream);
    k_count  <<<dim3(B_ / 256), dim3(256), 0, stream>>>(label, counts);
    k_offsets<<<dim3(1),        dim3(64),  0, stream>>>(counts, offsets);
    k_scatter<<<dim3(B_ / 256), dim3(256), 0, stream>>>(label, offsets, cursors, row_ids);
    k_prep   <<<dim3(2048),     dim3(256), 0, stream>>>(
        (const float4*)img, row_ids, (const float4*)Wenc, (const float4*)Wdec,
        (bf16x4*)imgG, (bf16x4*)We16, (bf16x4*)Wd16);
    enc_kernel<<<dim3(C_ / 128, B_ / 128, E_), dim3(512), 0, stream>>>(
        imgG, We16, benc, counts, offsets, code);
    dec_kernel<<<dim3(D_ / 128, B_ / 128, E_), dim3(256), 0, stream>>>(
        imgG, Wd16, bdec, row_ids, counts, offsets, code, out + 1, loss);
    k_final<<<dim3(1), dim3(64), 0, stream>>>(loss, out);
}